// Round 3
// baseline (295.502 us; speedup 1.0000x reference)
//
#include <hip/hip_runtime.h>

typedef __attribute__((ext_vector_type(8))) short short8;
typedef __attribute__((ext_vector_type(4))) float f32x4;

#define SEQ 2048
#define NB 2
#define HID 1024
#define NH 16
#define HD 64
#define MS (NB * SEQ)  // 4096 rows

#define QSCALE 0.18033688011112042f  // 0.125 * log2(e): softmax done in exp2 domain

typedef const __attribute__((address_space(1))) unsigned int* gptr_t;
typedef __attribute__((address_space(3))) unsigned int* lptr_t;

__device__ inline ushort f2bf(float f) {
  union { float f; unsigned u; } x; x.f = f;
  unsigned r = x.u + 0x7fffu + ((x.u >> 16) & 1u);
  return (ushort)(r >> 16);
}

__device__ inline unsigned cvt_pk_bf16(float lo, float hi) {
  unsigned r;
  asm volatile("v_cvt_pk_bf16_f32 %0, %1, %2" : "=v"(r) : "v"(lo), "v"(hi));
  return r;
}

// ---------------- casts ----------------
__global__ void cast3(const float* __restrict__ a, const float* __restrict__ b,
                      const float* __restrict__ c, ushort* __restrict__ oa,
                      ushort* __restrict__ ob, ushort* __restrict__ oc, int n4) {
  const int z = blockIdx.y;
  const float* in = (z == 0) ? a : (z == 1) ? b : c;
  ushort* out = (z == 0) ? oa : (z == 1) ? ob : oc;
  int i = blockIdx.x * 256 + threadIdx.x;
  if (i >= n4) return;
  float4 v = reinterpret_cast<const float4*>(in)[i];
  ushort4 o;
  o.x = f2bf(v.x); o.y = f2bf(v.y); o.z = f2bf(v.z); o.w = f2bf(v.w);
  reinterpret_cast<ushort4*>(out)[i] = o;
}

__global__ void cast4(const float* __restrict__ a, const float* __restrict__ b,
                      const float* __restrict__ c, const float* __restrict__ d,
                      ushort* __restrict__ oa, ushort* __restrict__ ob,
                      ushort* __restrict__ oc, ushort* __restrict__ od, int n4) {
  const int z = blockIdx.y;
  const float* in = (z == 0) ? a : (z == 1) ? b : (z == 2) ? c : d;
  ushort* out = (z == 0) ? oa : (z == 1) ? ob : (z == 2) ? oc : od;
  int i = blockIdx.x * 256 + threadIdx.x;
  if (i >= n4) return;
  float4 v = reinterpret_cast<const float4*>(in)[i];
  ushort4 o;
  o.x = f2bf(v.x); o.y = f2bf(v.y); o.z = f2bf(v.z); o.w = f2bf(v.w);
  reinterpret_cast<ushort4*>(out)[i] = o;
}

// ---------------- GEMM body: C[M,N] = A[M,K] * B[N,K]^T + bias ----------------
// BM=128, BK=32. OUT: 0 = f32, 1 = bf16, 2 = bf16 * QSCALE, 3 = bf16 transposed to VT[b][h][d][s]
template <int BN, int OUT>
__device__ __forceinline__ void gemm_body(const ushort* __restrict__ A,
                                          const ushort* __restrict__ B,
                                          const float* __restrict__ bias,
                                          void* __restrict__ Out,
                                          ushort* As, ushort* Bs) {
  constexpr int NJ = BN / 32;  // B-frags per wave
  const int tid = threadIdx.x;
  const int wave = tid >> 6, lane = tid & 63;
  const int lr = lane & 15, lg = lane >> 4;
  const int wr = wave >> 1, wc = wave & 1;  // 2x2 waves
  const int bm = blockIdx.y, bn = blockIdx.x;

  f32x4 acc[4][NJ];
#pragma unroll
  for (int i = 0; i < 4; ++i)
#pragma unroll
    for (int j = 0; j < NJ; ++j) acc[i][j] = (f32x4)(0.f);

  const int l4 = lane >> 2;        // row within 16-row chunk
  const int lc = (lane & 3) * 8;   // col elements

  for (int k0 = 0; k0 < HID; k0 += 32) {
#pragma unroll
    for (int c = 0; c < 2; ++c) {
      const int chunk = wave * 2 + c;
      const ushort* ga = &A[(size_t)(bm * 128 + chunk * 16 + l4) * HID + k0 + lc];
      __builtin_amdgcn_global_load_lds((gptr_t)(const void*)ga, (lptr_t)(void*)&As[chunk * 512], 16, 0, 0);
    }
    if (BN == 128) {
#pragma unroll
      for (int c = 0; c < 2; ++c) {
        const int chunk = wave * 2 + c;
        const ushort* gb = &B[(size_t)(bn * BN + chunk * 16 + l4) * HID + k0 + lc];
        __builtin_amdgcn_global_load_lds((gptr_t)(const void*)gb, (lptr_t)(void*)&Bs[chunk * 512], 16, 0, 0);
      }
    } else {
      const ushort* gb = &B[(size_t)(bn * BN + wave * 16 + l4) * HID + k0 + lc];
      __builtin_amdgcn_global_load_lds((gptr_t)(const void*)gb, (lptr_t)(void*)&Bs[wave * 512], 16, 0, 0);
    }
    __syncthreads();
    short8 af[4], bf[NJ];
#pragma unroll
    for (int i = 0; i < 4; ++i)
      af[i] = *reinterpret_cast<const short8*>(&As[(wr * 64 + i * 16 + lr) * 32 + lg * 8]);
#pragma unroll
    for (int j = 0; j < NJ; ++j)
      bf[j] = *reinterpret_cast<const short8*>(&Bs[(wc * (BN / 2) + j * 16 + lr) * 32 + lg * 8]);
#pragma unroll
    for (int i = 0; i < 4; ++i)
#pragma unroll
      for (int j = 0; j < NJ; ++j)
        acc[i][j] = __builtin_amdgcn_mfma_f32_16x16x32_bf16(af[i], bf[j], acc[i][j], 0, 0, 0);
    __syncthreads();
  }

#pragma unroll
  for (int i = 0; i < 4; ++i)
#pragma unroll
    for (int j = 0; j < NJ; ++j) {
      const int row0 = bm * 128 + wr * 64 + i * 16 + lg * 4;
      const int col = bn * BN + wc * (BN / 2) + j * 16 + lr;
      const float bv = bias[col];
      if (OUT == 0) {
#pragma unroll
        for (int r = 0; r < 4; ++r)
          ((float*)Out)[(size_t)(row0 + r) * HID + col] = acc[i][j][r] + bv;
      } else if (OUT == 1) {
#pragma unroll
        for (int r = 0; r < 4; ++r)
          ((ushort*)Out)[(size_t)(row0 + r) * HID + col] = f2bf(acc[i][j][r] + bv);
      } else if (OUT == 2) {
#pragma unroll
        for (int r = 0; r < 4; ++r)
          ((ushort*)Out)[(size_t)(row0 + r) * HID + col] = f2bf((acc[i][j][r] + bv) * QSCALE);
      } else {
        // transposed V: VT[((b*NH + h)*HD + d)*SEQ + s], b=row>>11, s=row&2047, h=col>>6, d=col&63
        uint2 w;
        w.x = cvt_pk_bf16(acc[i][j][0] + bv, acc[i][j][1] + bv);
        w.y = cvt_pk_bf16(acc[i][j][2] + bv, acc[i][j][3] + bv);
        size_t off = ((size_t)((row0 >> 11) * NH + (col >> 6)) << 17) +
                     ((size_t)(col & 63) << 11) + (size_t)(row0 & 2047);
        *reinterpret_cast<uint2*>(&((ushort*)Out)[off]) = w;
      }
    }
}

__global__ __launch_bounds__(256) void gemm_qkv(const ushort* __restrict__ A0, const ushort* __restrict__ A1,
                                                const ushort* __restrict__ A2, const ushort* __restrict__ W0,
                                                const ushort* __restrict__ W1, const ushort* __restrict__ W2,
                                                const float* __restrict__ b0, const float* __restrict__ b1,
                                                const float* __restrict__ b2, ushort* __restrict__ O0,
                                                ushort* __restrict__ O1, ushort* __restrict__ O2) {
  __shared__ alignas(16) ushort As[128 * 32];
  __shared__ alignas(16) ushort Bs[128 * 32];
  const int z = blockIdx.z;
  if (z == 0)      gemm_body<128, 2>(A0, W0, b0, O0, As, Bs);  // Q: pre-scaled
  else if (z == 1) gemm_body<128, 1>(A1, W1, b1, O1, As, Bs);  // K
  else             gemm_body<128, 3>(A2, W2, b2, O2, As, Bs);  // V: transposed
}

__global__ __launch_bounds__(256) void gemm_wo(const ushort* __restrict__ A, const ushort* __restrict__ W,
                                               const float* __restrict__ bias, float* __restrict__ O) {
  __shared__ alignas(16) ushort As[128 * 32];
  __shared__ alignas(16) ushort Bs[64 * 32];
  gemm_body<64, 0>(A, W, bias, O, As, Bs);
}

// ---------------- flash attention ----------------
// grid (SEQ/64, NB*NH), 256 threads = 4 waves, each wave owns 16 q-rows.
// Q pre-scaled by QSCALE; softmax in exp2 domain. K and V^T both staged via
// global_load_lds (pre-swizzled source) + XOR-swizzled ds_read_b128, double-buffered.
__global__ __launch_bounds__(256) void attn_kernel(const ushort* __restrict__ Q,
                                                   const ushort* __restrict__ Kp,
                                                   const ushort* __restrict__ VT,
                                                   ushort* __restrict__ Op) {
  __shared__ alignas(16) ushort Ks[2 * 4096];
  __shared__ alignas(16) ushort Vs[2 * 4096];

  const int qt = blockIdx.x;
  const int bh = blockIdx.y;
  const int b = bh >> 4, h = bh & 15;
  const int tid = threadIdx.x;
  const int wave = tid >> 6;
  const int lane = tid & 63;
  const int lr = lane & 15;
  const int lg = lane >> 4;

  const size_t base = (size_t)b * SEQ * HID + h * HD;      // Q, K, O (token-major)
  const size_t vtbase = (size_t)bh * HD * SEQ;             // VT (d-major)

  // Q fragments (B-operand: rows = q)
  short8 qf[2];
  const int qrow = qt * 64 + wave * 16 + lr;
#pragma unroll
  for (int kk = 0; kk < 2; ++kk)
    qf[kk] = *reinterpret_cast<const short8*>(&Q[base + (size_t)qrow * HID + kk * 32 + lg * 8]);

  f32x4 acc[4];  // O^T: acc[nd][r] = O[q=lr][d = nd*16 + lg*4 + r]
#pragma unroll
  for (int nd = 0; nd < 4; ++nd) acc[nd] = (f32x4)(0.f);
  float mrun = -1e30f, lrun = 0.f;

  const int rsub = lane >> 3;                       // row within 8-row chunk
  const int srcsl = ((lane & 7) ^ rsub) * 8;        // pre-swizzled source col (ushorts)
  const int s0 = lr + ((lg & 1) << 5);              // P-redistribution source lanes
  const int s1v = s0 + 16;

  auto stage = [&](int buf, int kt) {
#pragma unroll
    for (int c = 0; c < 2; ++c) {
      const int chunk = wave * 2 + c;
      const int row = chunk * 8 + rsub;  // K: key row; VT: d row
      const ushort* gk = &Kp[base + (size_t)(kt * 64 + row) * HID + srcsl];
      __builtin_amdgcn_global_load_lds((gptr_t)(const void*)gk,
                                       (lptr_t)(void*)&Ks[buf * 4096 + chunk * 512], 16, 0, 0);
      const ushort* gv = &VT[vtbase + (size_t)row * SEQ + kt * 64 + srcsl];
      __builtin_amdgcn_global_load_lds((gptr_t)(const void*)gv,
                                       (lptr_t)(void*)&Vs[buf * 4096 + chunk * 512], 16, 0, 0);
    }
  };

  stage(0, 0);
  __syncthreads();

  int cur = 0;
  for (int kt = 0; kt < SEQ / 64; ++kt) {
    const int nxt = (kt + 1 < SEQ / 64) ? kt + 1 : 0;
    stage(cur ^ 1, nxt);

    const char* kb = (const char*)&Ks[cur * 4096];
    const char* vb = (const char*)&Vs[cur * 4096];

    // ---- S^T = K Q^T: sa[n][r] = S[k = n*16 + lg*4 + r][q = lr] (already * QSCALE) ----
    f32x4 sa[4];
#pragma unroll
    for (int n = 0; n < 4; ++n) sa[n] = (f32x4)(0.f);
#pragma unroll
    for (int kk = 0; kk < 2; ++kk) {
      short8 kf[4];
#pragma unroll
      for (int n = 0; n < 4; ++n)
        kf[n] = *reinterpret_cast<const short8*>(
            kb + (n * 16 + lr) * 128 + ((kk * 64 + lg * 16) ^ ((lr & 7) << 4)));
#pragma unroll
      for (int n = 0; n < 4; ++n)
        sa[n] = __builtin_amdgcn_mfma_f32_16x16x32_bf16(kf[n], qf[kk], sa[n], 0, 0, 0);
    }

    // ---- online softmax (exp2 domain), fully in-register ----
    float pmax = sa[0][0];
#pragma unroll
    for (int n = 0; n < 4; ++n)
#pragma unroll
      for (int r = 0; r < 4; ++r) pmax = fmaxf(pmax, sa[n][r]);
    pmax = fmaxf(pmax, __shfl_xor(pmax, 16, 64));
    pmax = fmaxf(pmax, __shfl_xor(pmax, 32, 64));
    if (__any(pmax > mrun + 8.f)) {  // defer-max (T13): p bounded by 2^8
      const float mnew = fmaxf(mrun, pmax);
      const float corr = exp2f(mrun - mnew);
      mrun = mnew;
      lrun *= corr;
#pragma unroll
      for (int nd = 0; nd < 4; ++nd) acc[nd] *= corr;
    }
    float psum = 0.f;
#pragma unroll
    for (int n = 0; n < 4; ++n)
#pragma unroll
      for (int r = 0; r < 4; ++r) {
        float p = exp2f(sa[n][r] - mrun);
        sa[n][r] = p;
        psum += p;
      }
    psum += __shfl_xor(psum, 16, 64);
    psum += __shfl_xor(psum, 32, 64);
    lrun += psum;

    // ---- V^T fragments (A-operand: rows = d), XOR-swizzled reads ----
    short8 vtf[4][2];
#pragma unroll
    for (int nd = 0; nd < 4; ++nd)
#pragma unroll
      for (int kk = 0; kk < 2; ++kk)
        vtf[nd][kk] = *reinterpret_cast<const short8*>(
            vb + (nd * 16 + lr) * 128 + ((kk * 64 + lg * 16) ^ ((lr & 7) << 4)));

    // ---- P pack (cvt_pk) + redistribution + O^T += V^T P^T ----
#pragma unroll
    for (int kk = 0; kk < 2; ++kk) {
      unsigned pw0 = 0, pw1 = 0, pw2 = 0, pw3 = 0;
#pragma unroll
      for (int half = 0; half < 2; ++half) {
        const int nsel = kk * 2 + half;
        unsigned w0 = cvt_pk_bf16(sa[nsel][0], sa[nsel][1]);
        unsigned w1 = cvt_pk_bf16(sa[nsel][2], sa[nsel][3]);
        int d0 = __shfl((int)w0, s0, 64);
        int d1 = __shfl((int)w1, s0, 64);
        int d2 = __shfl((int)w0, s1v, 64);
        int d3 = __shfl((int)w1, s1v, 64);
        const bool take = ((lg >> 1) == half);
        pw0 = take ? (unsigned)d0 : pw0;
        pw1 = take ? (unsigned)d1 : pw1;
        pw2 = take ? (unsigned)d2 : pw2;
        pw3 = take ? (unsigned)d3 : pw3;
      }
      union { unsigned u[4]; short8 v; } pu;
      pu.u[0] = pw0; pu.u[1] = pw1; pu.u[2] = pw2; pu.u[3] = pw3;
#pragma unroll
      for (int nd = 0; nd < 4; ++nd)
        acc[nd] = __builtin_amdgcn_mfma_f32_16x16x32_bf16(vtf[nd][kk], pu.v, acc[nd], 0, 0, 0);
    }
    __syncthreads();
    cur ^= 1;
  }

  // ---- normalize and write ----
  const float linv = 1.f / lrun;
#pragma unroll
  for (int nd = 0; nd < 4; ++nd) {
    uint2 o;
    o.x = cvt_pk_bf16(acc[nd][0] * linv, acc[nd][1] * linv);
    o.y = cvt_pk_bf16(acc[nd][2] * linv, acc[nd][3] * linv);
    *reinterpret_cast<uint2*>(&Op[base + (size_t)qrow * HID + nd * 16 + lg * 4]) = o;
  }
}

// ---------------- launch ----------------
extern "C" void kernel_launch(void* const* d_in, const int* in_sizes, int n_in,
                              void* d_out, int out_size, void* d_ws, size_t ws_size,
                              hipStream_t stream) {
  const float* query = (const float*)d_in[0];
  const float* key   = (const float*)d_in[1];
  const float* value = (const float*)d_in[2];
  const float* Wq = (const float*)d_in[3];
  const float* bq = (const float*)d_in[4];
  const float* Wk = (const float*)d_in[5];
  const float* bk = (const float*)d_in[6];
  const float* Wv = (const float*)d_in[7];
  const float* bv = (const float*)d_in[8];
  const float* Wo = (const float*)d_in[9];
  const float* bo = (const float*)d_in[10];

  const size_t actElems = (size_t)MS * HID;  // 4194304
  const size_t wElems = (size_t)HID * HID;   // 1048576
  char* ws = (char*)d_ws;
  ushort* qb = (ushort*)(ws + 0);
  ushort* kb = (ushort*)(ws + actElems * 2);
  ushort* vb = (ushort*)(ws + actElems * 4);
  ushort* wq = (ushort*)(ws + actElems * 6);
  ushort* wk = (ushort*)(ws + actElems * 6 + wElems * 2);
  ushort* wv = (ushort*)(ws + actElems * 6 + wElems * 4);
  ushort* wo = (ushort*)(ws + actElems * 6 + wElems * 6);
  ushort* Qp   = (ushort*)(ws + actElems * 6 + wElems * 8);
  ushort* Kp   = (ushort*)(ws + actElems * 8 + wElems * 8);
  ushort* VTp  = (ushort*)(ws + actElems * 10 + wElems * 8);
  ushort* attn = (ushort*)(ws + actElems * 12 + wElems * 8);

  dim3 cg3((unsigned)(actElems / 4 / 256), 3);
  cast3<<<cg3, 256, 0, stream>>>(query, key, value, qb, kb, vb, (int)(actElems / 4));
  dim3 cg4((unsigned)(wElems / 4 / 256), 4);
  cast4<<<cg4, 256, 0, stream>>>(Wq, Wk, Wv, Wo, wq, wk, wv, wo, (int)(wElems / 4));

  dim3 gq(HID / 128, MS / 128, 3);  // 768 blocks
  gemm_qkv<<<gq, 256, 0, stream>>>(qb, kb, vb, wq, wk, wv, bq, bk, bv, Qp, Kp, VTp);

  dim3 ga(SEQ / 64, NB * NH);  // (32, 32), qt-major for K/V L2 reuse
  attn_kernel<<<ga, 256, 0, stream>>>(Qp, Kp, VTp, attn);

  dim3 go(HID / 64, MS / 128);  // (16, 32) = 512 blocks
  gemm_wo<<<go, 256, 0, stream>>>(attn, wo, bo, (float*)d_out);
}

// Round 5
// 251.477 us; speedup vs baseline: 1.1751x; 1.1751x over previous
//
#include <hip/hip_runtime.h>

typedef __attribute__((ext_vector_type(8))) short short8;
typedef __attribute__((ext_vector_type(4))) float f32x4;
typedef __attribute__((ext_vector_type(16))) float f32x16;

#define SEQ 2048
#define NB 2
#define HID 1024
#define NH 16
#define HD 64
#define MS (NB * SEQ)  // 4096 rows

#define QSCALE 0.18033688011112042f  // 0.125 * log2(e): softmax in exp2 domain

typedef const __attribute__((address_space(1))) unsigned int* gptr_t;
typedef __attribute__((address_space(3))) unsigned int* lptr_t;

__device__ inline ushort f2bf(float f) {
  union { float f; unsigned u; } x; x.f = f;
  unsigned r = x.u + 0x7fffu + ((x.u >> 16) & 1u);
  return (ushort)(r >> 16);
}

__device__ __forceinline__ unsigned cvt_pk_bf16(float lo, float hi) {
  unsigned r;
  asm("v_cvt_pk_bf16_f32 %0, %1, %2" : "=v"(r) : "v"(lo), "v"(hi));
  return r;
}

// ---------------- casts ----------------
__global__ void cast3(const float* __restrict__ a, const float* __restrict__ b,
                      const float* __restrict__ c, ushort* __restrict__ oa,
                      ushort* __restrict__ ob, ushort* __restrict__ oc, int n4) {
  const int z = blockIdx.y;
  const float* in = (z == 0) ? a : (z == 1) ? b : c;
  ushort* out = (z == 0) ? oa : (z == 1) ? ob : oc;
  int i = blockIdx.x * 256 + threadIdx.x;
  if (i >= n4) return;
  float4 v = reinterpret_cast<const float4*>(in)[i];
  ushort4 o;
  o.x = f2bf(v.x); o.y = f2bf(v.y); o.z = f2bf(v.z); o.w = f2bf(v.w);
  reinterpret_cast<ushort4*>(out)[i] = o;
}

__global__ void cast4(const float* __restrict__ a, const float* __restrict__ b,
                      const float* __restrict__ c, const float* __restrict__ d,
                      ushort* __restrict__ oa, ushort* __restrict__ ob,
                      ushort* __restrict__ oc, ushort* __restrict__ od, int n4) {
  const int z = blockIdx.y;
  const float* in = (z == 0) ? a : (z == 1) ? b : (z == 2) ? c : d;
  ushort* out = (z == 0) ? oa : (z == 1) ? ob : (z == 2) ? oc : od;
  int i = blockIdx.x * 256 + threadIdx.x;
  if (i >= n4) return;
  float4 v = reinterpret_cast<const float4*>(in)[i];
  ushort4 o;
  o.x = f2bf(v.x); o.y = f2bf(v.y); o.z = f2bf(v.z); o.w = f2bf(v.w);
  reinterpret_cast<ushort4*>(out)[i] = o;
}

// ---------------- GEMM body: C[M,N] = A[M,K] * B[N,K]^T + bias ----------------
// BM=128, BK=32. OUT: 0 = f32, 1 = bf16, 2 = bf16 * QSCALE
template <int BN, int OUT>
__device__ __forceinline__ void gemm_body(const ushort* __restrict__ A,
                                          const ushort* __restrict__ B,
                                          const float* __restrict__ bias,
                                          void* __restrict__ Out,
                                          ushort* As, ushort* Bs) {
  constexpr int NJ = BN / 32;
  const int tid = threadIdx.x;
  const int wave = tid >> 6, lane = tid & 63;
  const int lr = lane & 15, lg = lane >> 4;
  const int wr = wave >> 1, wc = wave & 1;
  const int bm = blockIdx.y, bn = blockIdx.x;

  f32x4 acc[4][NJ];
#pragma unroll
  for (int i = 0; i < 4; ++i)
#pragma unroll
    for (int j = 0; j < NJ; ++j) acc[i][j] = (f32x4)(0.f);

  const int l4 = lane >> 2;
  const int lc = (lane & 3) * 8;

  for (int k0 = 0; k0 < HID; k0 += 32) {
#pragma unroll
    for (int c = 0; c < 2; ++c) {
      const int chunk = wave * 2 + c;
      const ushort* ga = &A[(size_t)(bm * 128 + chunk * 16 + l4) * HID + k0 + lc];
      __builtin_amdgcn_global_load_lds((gptr_t)(const void*)ga, (lptr_t)(void*)&As[chunk * 512], 16, 0, 0);
    }
    if (BN == 128) {
#pragma unroll
      for (int c = 0; c < 2; ++c) {
        const int chunk = wave * 2 + c;
        const ushort* gb = &B[(size_t)(bn * BN + chunk * 16 + l4) * HID + k0 + lc];
        __builtin_amdgcn_global_load_lds((gptr_t)(const void*)gb, (lptr_t)(void*)&Bs[chunk * 512], 16, 0, 0);
      }
    } else {
      const ushort* gb = &B[(size_t)(bn * BN + wave * 16 + l4) * HID + k0 + lc];
      __builtin_amdgcn_global_load_lds((gptr_t)(const void*)gb, (lptr_t)(void*)&Bs[wave * 512], 16, 0, 0);
    }
    __syncthreads();
    short8 af[4], bf[NJ];
#pragma unroll
    for (int i = 0; i < 4; ++i)
      af[i] = *reinterpret_cast<const short8*>(&As[(wr * 64 + i * 16 + lr) * 32 + lg * 8]);
#pragma unroll
    for (int j = 0; j < NJ; ++j)
      bf[j] = *reinterpret_cast<const short8*>(&Bs[(wc * (BN / 2) + j * 16 + lr) * 32 + lg * 8]);
#pragma unroll
    for (int i = 0; i < 4; ++i)
#pragma unroll
      for (int j = 0; j < NJ; ++j)
        acc[i][j] = __builtin_amdgcn_mfma_f32_16x16x32_bf16(af[i], bf[j], acc[i][j], 0, 0, 0);
    __syncthreads();
  }

#pragma unroll
  for (int i = 0; i < 4; ++i)
#pragma unroll
    for (int j = 0; j < NJ; ++j) {
      const int row0 = bm * 128 + wr * 64 + i * 16 + lg * 4;
      const int col = bn * BN + wc * (BN / 2) + j * 16 + lr;
      const float bv = bias[col];
#pragma unroll
      for (int r = 0; r < 4; ++r) {
        float v = acc[i][j][r] + bv;
        if (OUT == 0)
          ((float*)Out)[(size_t)(row0 + r) * HID + col] = v;
        else if (OUT == 1)
          ((ushort*)Out)[(size_t)(row0 + r) * HID + col] = f2bf(v);
        else
          ((ushort*)Out)[(size_t)(row0 + r) * HID + col] = f2bf(v * QSCALE);
      }
    }
}

__global__ __launch_bounds__(256) void gemm_qkv(const ushort* __restrict__ A0, const ushort* __restrict__ A1,
                                                const ushort* __restrict__ A2, const ushort* __restrict__ W0,
                                                const ushort* __restrict__ W1, const ushort* __restrict__ W2,
                                                const float* __restrict__ b0, const float* __restrict__ b1,
                                                const float* __restrict__ b2, ushort* __restrict__ O0,
                                                ushort* __restrict__ O1, ushort* __restrict__ O2) {
  __shared__ alignas(16) ushort As[128 * 32];
  __shared__ alignas(16) ushort Bs[128 * 32];
  const int z = blockIdx.z;
  if (z == 0)      gemm_body<128, 2>(A0, W0, b0, O0, As, Bs);  // Q pre-scaled
  else if (z == 1) gemm_body<128, 1>(A1, W1, b1, O1, As, Bs);  // K
  else             gemm_body<128, 1>(A2, W2, b2, O2, As, Bs);  // V (row-major)
}

__global__ __launch_bounds__(256) void gemm_wo(const ushort* __restrict__ A, const ushort* __restrict__ W,
                                               const float* __restrict__ bias, float* __restrict__ O) {
  __shared__ alignas(16) ushort As[128 * 32];
  __shared__ alignas(16) ushort Bs[64 * 32];
  gemm_body<64, 0>(A, W, bias, O, As, Bs);
}

// ---------------- V transpose: Vp[b*S+s][h*64+d] -> VT[bh][d][s] ----------------
__global__ __launch_bounds__(256) void vt_kernel(const ushort* __restrict__ Vp, ushort* __restrict__ VT) {
  __shared__ ushort Lt[64][68];
  const int sb = blockIdx.x, bh = blockIdx.y;
  const int b = bh >> 4, h = bh & 15;
  const int t = threadIdx.x;
  const int s4 = (t & 15) * 4, d4 = (t >> 4) * 4;
  ushort v[4][4];
#pragma unroll
  for (int r = 0; r < 4; ++r) {
    ushort4 x = *reinterpret_cast<const ushort4*>(
        &Vp[(size_t)(b * SEQ + sb * 64 + s4 + r) * HID + h * 64 + d4]);
    v[r][0] = x.x; v[r][1] = x.y; v[r][2] = x.z; v[r][3] = x.w;
  }
#pragma unroll
  for (int j = 0; j < 4; ++j) {
    ushort4 y; y.x = v[0][j]; y.y = v[1][j]; y.z = v[2][j]; y.w = v[3][j];
    *reinterpret_cast<ushort4*>(&Lt[d4 + j][s4]) = y;
  }
  __syncthreads();
  const int dl = t >> 2, s0 = (t & 3) * 16;
  ushort4 o[4];
#pragma unroll
  for (int p = 0; p < 4; ++p) o[p] = *reinterpret_cast<const ushort4*>(&Lt[dl][s0 + p * 4]);
  ushort* dst = &VT[((size_t)bh * HD + dl) * SEQ + sb * 64 + s0];
#pragma unroll
  for (int p = 0; p < 4; ++p) *reinterpret_cast<ushort4*>(&dst[p * 4]) = o[p];
}

// ---------------- flash attention: 32x32 MFMA, swapped QK^T, split-KV ----------------
// grid (NB*NH, SEQ/128), 512 threads = 8 waves.
// wave w: q-sub (w&3)*32, kv-half (w>>2). Per wave: 16 KV tiles of 64 keys.
__device__ __forceinline__ short8 ldfrag(const char* tb, int r, int g) {
  return *reinterpret_cast<const short8*>(tb + r * 128 + ((g * 16) ^ ((r & 7) << 4)));
}

__global__ __launch_bounds__(512, 4) void attn_kernel(const ushort* __restrict__ Q,
                                                      const ushort* __restrict__ Kp,
                                                      const ushort* __restrict__ VT,
                                                      ushort* __restrict__ Op) {
  __shared__ alignas(16) ushort lds[32768];  // K: 4 tiles x 4096 ush; V: +16384. 64KB.

  const int bh = blockIdx.x;
  const int b = bh >> 4, h = bh & 15;
  const int qt = blockIdx.y;
  const int tid = threadIdx.x;
  const int w = tid >> 6, lane = tid & 63;
  const int q = lane & 31, hi = lane >> 5;
  const int qsub = w & 3, chf = w >> 2;

  const size_t base = (size_t)b * SEQ * HID + h * HD;
  const size_t vtbase = (size_t)bh * HD * SEQ;

  const int qrow = qt * 128 + qsub * 32 + q;
  short8 qf[4];
#pragma unroll
  for (int s = 0; s < 4; ++s)
    qf[s] = *reinterpret_cast<const short8*>(&Q[base + (size_t)qrow * HID + s * 16 + hi * 8]);

  f32x16 acc0 = (f32x16)(0.f), acc1 = (f32x16)(0.f);
  float mrun = -3e38f;
  float ps0 = 0.f, ps1 = 0.f, ps2 = 0.f, ps3 = 0.f;

  // staging role: tsel 0=K.h0 1=K.h1 2=V.h0 3=V.h1; part = rows half
  const int tsel = w >> 1, part = w & 1, sh = tsel & 1;
  const bool isK = tsel < 2;
  const int r8 = lane >> 3;
  const int sx = ((lane & 7) ^ r8) * 8;  // pre-swizzled source col (ushorts)

  auto stage = [&](int buf, int ktb) {
    const int kt = ktb + sh * 16;
#pragma unroll
    for (int c = 0; c < 4; ++c) {
      const int G = part * 4 + c, r = G * 8 + r8;
      const ushort* src;
      ushort* dst;
      if (isK) {
        src = &Kp[base + (size_t)(kt * 64 + r) * HID + sx];
        dst = &lds[(sh * 2 + buf) * 4096 + G * 512];
      } else {
        src = &VT[vtbase + (size_t)r * SEQ + kt * 64 + sx];
        dst = &lds[16384 + (sh * 2 + buf) * 4096 + G * 512];
      }
      __builtin_amdgcn_global_load_lds((gptr_t)(const void*)src, (lptr_t)(void*)dst, 16, 0, 0);
    }
  };

  // P-fragment builder: group Wg[0..3] (packed bf16 pairs, C/D reg order) ->
  // B-operand short8. hi=0 lane needs {W0,W1,partnerW0,partnerW1};
  // hi=1 needs {partnerW2,partnerW3,W2,W3}. Partner = lane ^ 32.
  auto mkfrag = [&](const unsigned* Wg) -> short8 {
    unsigned X0 = (unsigned)__shfl_xor((int)Wg[0], 32, 64);
    unsigned X1 = (unsigned)__shfl_xor((int)Wg[1], 32, 64);
    unsigned X2 = (unsigned)__shfl_xor((int)Wg[2], 32, 64);
    unsigned X3 = (unsigned)__shfl_xor((int)Wg[3], 32, 64);
    union { unsigned u[4]; short8 v; } p;
    p.u[0] = hi ? X2 : Wg[0];
    p.u[1] = hi ? X3 : Wg[1];
    p.u[2] = hi ? Wg[2] : X0;
    p.u[3] = hi ? Wg[3] : X1;
    return p.v;
  };

  stage(0, 0);
  __syncthreads();

  int buf = 0;
  for (int ktb = 0; ktb < 16; ++ktb) {
    stage(buf ^ 1, (ktb + 1) & 15);

    const char* kb = (const char*)lds + (chf * 2 + buf) * 8192;
    const char* vb = (const char*)lds + 32768 + (chf * 2 + buf) * 8192;

    // ---- S^T = K Q^T: s0 (k 0..31), s1 (k 32..63); col = q = lane&31 ----
    f32x16 s0 = (f32x16)(0.f), s1 = (f32x16)(0.f);
#pragma unroll
    for (int cs = 0; cs < 4; ++cs) {
      short8 a = ldfrag(kb, q, cs * 2 + hi);
      s0 = __builtin_amdgcn_mfma_f32_32x32x16_bf16(a, qf[cs], s0, 0, 0, 0);
    }
#pragma unroll
    for (int cs = 0; cs < 4; ++cs) {
      short8 a = ldfrag(kb, 32 + q, cs * 2 + hi);
      s1 = __builtin_amdgcn_mfma_f32_32x32x16_bf16(a, qf[cs], s1, 0, 0, 0);
    }

    // ---- online softmax (exp2 domain), in-register ----
    float t8[8];
#pragma unroll
    for (int i = 0; i < 8; ++i)
      t8[i] = fmaxf(fmaxf(s0[i], s0[i + 8]), fmaxf(s1[i], s1[i + 8]));
    float pm = fmaxf(fmaxf(fmaxf(t8[0], t8[4]), fmaxf(t8[1], t8[5])),
                     fmaxf(fmaxf(t8[2], t8[6]), fmaxf(t8[3], t8[7])));
    pm = fmaxf(pm, __shfl_xor(pm, 32, 64));  // combine lane ^ 32 (same q)
    if (__any(pm > mrun + 8.f)) {  // defer-max (T13)
      const float mnew = fmaxf(mrun, pm);
      const float corr = __builtin_amdgcn_exp2f(mrun - mnew);
      mrun = mnew;
      ps0 *= corr; ps1 *= corr; ps2 *= corr; ps3 *= corr;
#pragma unroll
      for (int i = 0; i < 16; ++i) { acc0[i] *= corr; acc1[i] *= corr; }
    }
#pragma unroll
    for (int i = 0; i < 16; ++i) {
      s0[i] = __builtin_amdgcn_exp2f(s0[i] - mrun);
      s1[i] = __builtin_amdgcn_exp2f(s1[i] - mrun);
    }
    float a8[8];
#pragma unroll
    for (int i = 0; i < 8; ++i) a8[i] = (s0[i] + s0[i + 8]) + (s1[i] + s1[i + 8]);
    ps0 += a8[0] + a8[4]; ps1 += a8[1] + a8[5];
    ps2 += a8[2] + a8[6]; ps3 += a8[3] + a8[7];

    // ---- P pack + cross-half exchange + PV per k-step ----
    {
      unsigned W[8];
#pragma unroll
      for (int i = 0; i < 8; ++i) W[i] = cvt_pk_bf16(s0[2 * i], s0[2 * i + 1]);
      short8 p0 = mkfrag(W);       // keys 0..15
      short8 p1 = mkfrag(W + 4);   // keys 16..31
      short8 vf;
      vf = ldfrag(vb, q,      0 + hi); acc0 = __builtin_amdgcn_mfma_f32_32x32x16_bf16(vf, p0, acc0, 0, 0, 0);
      vf = ldfrag(vb, 32 + q, 0 + hi); acc1 = __builtin_amdgcn_mfma_f32_32x32x16_bf16(vf, p0, acc1, 0, 0, 0);
      vf = ldfrag(vb, q,      2 + hi); acc0 = __builtin_amdgcn_mfma_f32_32x32x16_bf16(vf, p1, acc0, 0, 0, 0);
      vf = ldfrag(vb, 32 + q, 2 + hi); acc1 = __builtin_amdgcn_mfma_f32_32x32x16_bf16(vf, p1, acc1, 0, 0, 0);
    }
    {
      unsigned W[8];
#pragma unroll
      for (int i = 0; i < 8; ++i) W[i] = cvt_pk_bf16(s1[2 * i], s1[2 * i + 1]);
      short8 p0 = mkfrag(W);       // keys 32..47
      short8 p1 = mkfrag(W + 4);   // keys 48..63
      short8 vf;
      vf = ldfrag(vb, q,      4 + hi); acc0 = __builtin_amdgcn_mfma_f32_32x32x16_bf16(vf, p0, acc0, 0, 0, 0);
      vf = ldfrag(vb, 32 + q, 4 + hi); acc1 = __builtin_amdgcn_mfma_f32_32x32x16_bf16(vf, p0, acc1, 0, 0, 0);
      vf = ldfrag(vb, q,      6 + hi); acc0 = __builtin_amdgcn_mfma_f32_32x32x16_bf16(vf, p1, acc0, 0, 0, 0);
      vf = ldfrag(vb, 32 + q, 6 + hi); acc1 = __builtin_amdgcn_mfma_f32_32x32x16_bf16(vf, p1, acc1, 0, 0, 0);
    }
    __syncthreads();
    buf ^= 1;
  }

  // ---- per-wave row sum (combine lane ^ 32) ----
  float lsum = (ps0 + ps1) + (ps2 + ps3);
  const float lfull = lsum + __shfl_xor(lsum, 32, 64);

  // ---- combine kv-halves via LDS overlay ----
  __syncthreads();
  float* fl = (float*)lds;
  const int p = w & 3;
  float* ob = fl + p * 2048 + lane * 32;
  if (w >= 4) {
#pragma unroll
    for (int i = 0; i < 4; ++i) {
      f32x4 x = {acc0[4 * i], acc0[4 * i + 1], acc0[4 * i + 2], acc0[4 * i + 3]};
      *reinterpret_cast<f32x4*>(ob + 4 * (i ^ (lane & 7))) = x;
    }
#pragma unroll
    for (int i = 0; i < 4; ++i) {
      f32x4 x = {acc1[4 * i], acc1[4 * i + 1], acc1[4 * i + 2], acc1[4 * i + 3]};
      *reinterpret_cast<f32x4*>(ob + 4 * ((i + 4) ^ (lane & 7))) = x;
    }
    fl[8192 + (p * 64 + lane) * 2] = mrun;
    fl[8192 + (p * 64 + lane) * 2 + 1] = lfull;
  }
  __syncthreads();
  if (w < 4) {
    const float m1 = fl[8192 + (p * 64 + lane) * 2];
    const float l1 = fl[8192 + (p * 64 + lane) * 2 + 1];
    float o1[32];
#pragma unroll
    for (int s = 0; s < 8; ++s) {
      f32x4 x = *reinterpret_cast<const f32x4*>(ob + 4 * (s ^ (lane & 7)));
      o1[4 * s] = x[0]; o1[4 * s + 1] = x[1]; o1[4 * s + 2] = x[2]; o1[4 * s + 3] = x[3];
    }
    const float mnew = fmaxf(mrun, m1);
    const float c0 = __builtin_amdgcn_exp2f(mrun - mnew);
    const float c1 = __builtin_amdgcn_exp2f(m1 - mnew);
    const float linv = 1.f / (lfull * c0 + l1 * c1);
#pragma unroll
    for (int g = 0; g < 4; ++g) {
      {
        float x0 = (acc0[4 * g + 0] * c0 + o1[4 * g + 0] * c1) * linv;
        float x1 = (acc0[4 * g + 1] * c0 + o1[4 * g + 1] * c1) * linv;
        float x2 = (acc0[4 * g + 2] * c0 + o1[4 * g + 2] * c1) * linv;
        float x3 = (acc0[4 * g + 3] * c0 + o1[4 * g + 3] * c1) * linv;
        uint2 wd; wd.x = cvt_pk_bf16(x0, x1); wd.y = cvt_pk_bf16(x2, x3);
        *reinterpret_cast<uint2*>(&Op[base + (size_t)qrow * HID + g * 8 + hi * 4]) = wd;
      }
      {
        float x0 = (acc1[4 * g + 0] * c0 + o1[16 + 4 * g + 0] * c1) * linv;
        float x1 = (acc1[4 * g + 1] * c0 + o1[16 + 4 * g + 1] * c1) * linv;
        float x2 = (acc1[4 * g + 2] * c0 + o1[16 + 4 * g + 2] * c1) * linv;
        float x3 = (acc1[4 * g + 3] * c0 + o1[16 + 4 * g + 3] * c1) * linv;
        uint2 wd; wd.x = cvt_pk_bf16(x0, x1); wd.y = cvt_pk_bf16(x2, x3);
        *reinterpret_cast<uint2*>(&Op[base + (size_t)qrow * HID + 32 + g * 8 + hi * 4]) = wd;
      }
    }
  }
}

// ---------------- launch ----------------
extern "C" void kernel_launch(void* const* d_in, const int* in_sizes, int n_in,
                              void* d_out, int out_size, void* d_ws, size_t ws_size,
                              hipStream_t stream) {
  const float* query = (const float*)d_in[0];
  const float* key   = (const float*)d_in[1];
  const float* value = (const float*)d_in[2];
  const float* Wq = (const float*)d_in[3];
  const float* bq = (const float*)d_in[4];
  const float* Wk = (const float*)d_in[5];
  const float* bk = (const float*)d_in[6];
  const float* Wv = (const float*)d_in[7];
  const float* bv = (const float*)d_in[8];
  const float* Wo = (const float*)d_in[9];
  const float* bo = (const float*)d_in[10];

  const size_t actElems = (size_t)MS * HID;  // 4194304
  const size_t wElems = (size_t)HID * HID;   // 1048576
  char* ws = (char*)d_ws;
  ushort* qb = (ushort*)(ws + 0);
  ushort* kb = (ushort*)(ws + actElems * 2);
  ushort* vb = (ushort*)(ws + actElems * 4);
  ushort* wq = (ushort*)(ws + actElems * 6);
  ushort* wk = (ushort*)(ws + actElems * 6 + wElems * 2);
  ushort* wv = (ushort*)(ws + actElems * 6 + wElems * 4);
  ushort* wo = (ushort*)(ws + actElems * 6 + wElems * 6);
  ushort* Qp   = (ushort*)(ws + actElems * 6 + wElems * 8);
  ushort* Kp   = (ushort*)(ws + actElems * 8 + wElems * 8);
  ushort* VTp  = (ushort*)(ws + actElems * 10 + wElems * 8);
  ushort* XB   = (ushort*)(ws + actElems * 12 + wElems * 8);  // Vp (pre-vt), then attn out

  dim3 cg3((unsigned)(actElems / 4 / 256), 3);
  cast3<<<cg3, 256, 0, stream>>>(query, key, value, qb, kb, vb, (int)(actElems / 4));
  dim3 cg4((unsigned)(wElems / 4 / 256), 4);
  cast4<<<cg4, 256, 0, stream>>>(Wq, Wk, Wv, Wo, wq, wk, wv, wo, (int)(wElems / 4));

  dim3 gq(HID / 128, MS / 128, 3);  // 768 blocks
  gemm_qkv<<<gq, 256, 0, stream>>>(qb, kb, vb, wq, wk, wv, bq, bk, bv, Qp, Kp, XB);

  dim3 gv(SEQ / 64, NB * NH);  // (32, 32)
  vt_kernel<<<gv, 256, 0, stream>>>(XB, VTp);

  dim3 ga(NB * NH, SEQ / 128);  // (32, 16) = 512 blocks x 512 threads; bh%8 pins XCD
  attn_kernel<<<ga, 512, 0, stream>>>(Qp, Kp, VTp, XB);

  dim3 go(HID / 64, MS / 128);  // (16, 32) = 512 blocks
  gemm_wo<<<go, 256, 0, stream>>>(XB, wo, bo, (float*)d_out);
}

// Round 7
// 237.314 us; speedup vs baseline: 1.2452x; 1.0597x over previous
//
#include <hip/hip_runtime.h>

typedef __attribute__((ext_vector_type(8))) short short8;
typedef __attribute__((ext_vector_type(4))) float f32x4;
typedef __attribute__((ext_vector_type(16))) float f32x16;

#define SEQ 2048
#define NB 2
#define HID 1024
#define NH 16
#define HD 64
#define MS (NB * SEQ)  // 4096 rows

#define QSCALE 0.18033688011112042f  // 0.125 * log2(e): softmax in exp2 domain

typedef const __attribute__((address_space(1))) unsigned int* gptr_t;
typedef __attribute__((address_space(3))) unsigned int* lptr_t;

__device__ inline ushort f2bf(float f) {
  union { float f; unsigned u; } x; x.f = f;
  unsigned r = x.u + 0x7fffu + ((x.u >> 16) & 1u);
  return (ushort)(r >> 16);
}

__device__ __forceinline__ unsigned cvt_pk_bf16(float lo, float hi) {
  unsigned r;
  asm("v_cvt_pk_bf16_f32 %0, %1, %2" : "=v"(r) : "v"(lo), "v"(hi));
  return r;
}

// ---------------- single cast dispatch ----------------
__global__ __launch_bounds__(256) void cast_all(
    const float* __restrict__ q, const float* __restrict__ k, const float* __restrict__ v,
    const float* __restrict__ w0, const float* __restrict__ w1, const float* __restrict__ w2,
    const float* __restrict__ w3, ushort* __restrict__ oq, ushort* __restrict__ ok,
    ushort* __restrict__ ov, ushort* __restrict__ o0, ushort* __restrict__ o1,
    ushort* __restrict__ o2, ushort* __restrict__ o3) {
  const int id = blockIdx.x;
  const float* in;
  ushort* out;
  int i;
  if (id < 12288) {
    const int z = id >> 12;
    in = (z == 0) ? q : (z == 1) ? k : v;
    out = (z == 0) ? oq : (z == 1) ? ok : ov;
    i = (id & 4095) * 256 + threadIdx.x;
  } else {
    const int z = (id - 12288) >> 10;
    in = (z == 0) ? w0 : (z == 1) ? w1 : (z == 2) ? w2 : w3;
    out = (z == 0) ? o0 : (z == 1) ? o1 : (z == 2) ? o2 : o3;
    i = ((id - 12288) & 1023) * 256 + threadIdx.x;
  }
  float4 vv = reinterpret_cast<const float4*>(in)[i];
  ushort4 o;
  o.x = f2bf(vv.x); o.y = f2bf(vv.y); o.z = f2bf(vv.z); o.w = f2bf(vv.w);
  reinterpret_cast<ushort4*>(out)[i] = o;
}

// ---------------- GEMM body: C[M,N] = A[M,K] * B[N,K]^T + bias ----------------
// BM=128, BK=32. OUT: 0 = f32, 1 = bf16, 2 = bf16 * QSCALE, 3 = bf16 transposed to VT[b][h][d][s]
template <int BN, int OUT>
__device__ __forceinline__ void gemm_body(const ushort* __restrict__ A,
                                          const ushort* __restrict__ B,
                                          const float* __restrict__ bias,
                                          void* __restrict__ Out,
                                          ushort* As, ushort* Bs, int bm, int bn) {
  constexpr int NJ = BN / 32;
  const int tid = threadIdx.x;
  const int wave = tid >> 6, lane = tid & 63;
  const int lr = lane & 15, lg = lane >> 4;
  const int wr = wave >> 1, wc = wave & 1;

  f32x4 acc[4][NJ];
#pragma unroll
  for (int i = 0; i < 4; ++i)
#pragma unroll
    for (int j = 0; j < NJ; ++j) acc[i][j] = (f32x4)(0.f);

  const int l4 = lane >> 2;
  const int lc = (lane & 3) * 8;

  for (int k0 = 0; k0 < HID; k0 += 32) {
#pragma unroll
    for (int c = 0; c < 2; ++c) {
      const int chunk = wave * 2 + c;
      const ushort* ga = &A[(size_t)(bm * 128 + chunk * 16 + l4) * HID + k0 + lc];
      __builtin_amdgcn_global_load_lds((gptr_t)(const void*)ga, (lptr_t)(void*)&As[chunk * 512], 16, 0, 0);
    }
    if (BN == 128) {
#pragma unroll
      for (int c = 0; c < 2; ++c) {
        const int chunk = wave * 2 + c;
        const ushort* gb = &B[(size_t)(bn * BN + chunk * 16 + l4) * HID + k0 + lc];
        __builtin_amdgcn_global_load_lds((gptr_t)(const void*)gb, (lptr_t)(void*)&Bs[chunk * 512], 16, 0, 0);
      }
    } else {
      const ushort* gb = &B[(size_t)(bn * BN + wave * 16 + l4) * HID + k0 + lc];
      __builtin_amdgcn_global_load_lds((gptr_t)(const void*)gb, (lptr_t)(void*)&Bs[wave * 512], 16, 0, 0);
    }
    __syncthreads();
    short8 af[4], bf[NJ];
#pragma unroll
    for (int i = 0; i < 4; ++i)
      af[i] = *reinterpret_cast<const short8*>(&As[(wr * 64 + i * 16 + lr) * 32 + lg * 8]);
#pragma unroll
    for (int j = 0; j < NJ; ++j)
      bf[j] = *reinterpret_cast<const short8*>(&Bs[(wc * (BN / 2) + j * 16 + lr) * 32 + lg * 8]);
#pragma unroll
    for (int i = 0; i < 4; ++i)
#pragma unroll
      for (int j = 0; j < NJ; ++j)
        acc[i][j] = __builtin_amdgcn_mfma_f32_16x16x32_bf16(af[i], bf[j], acc[i][j], 0, 0, 0);
    __syncthreads();
  }

#pragma unroll
  for (int i = 0; i < 4; ++i)
#pragma unroll
    for (int j = 0; j < NJ; ++j) {
      const int row0 = bm * 128 + wr * 64 + i * 16 + lg * 4;
      const int col = bn * BN + wc * (BN / 2) + j * 16 + lr;
      const float bv = bias[col];
      if (OUT == 3) {
        // transposed V: VT[((b*NH+h)*HD+d)*SEQ+s]; verified on HW in round 3
        uint2 w;
        w.x = cvt_pk_bf16(acc[i][j][0] + bv, acc[i][j][1] + bv);
        w.y = cvt_pk_bf16(acc[i][j][2] + bv, acc[i][j][3] + bv);
        size_t off = ((size_t)((row0 >> 11) * NH + (col >> 6)) << 17) +
                     ((size_t)(col & 63) << 11) + (size_t)(row0 & 2047);
        *reinterpret_cast<uint2*>(&((ushort*)Out)[off]) = w;
      } else {
#pragma unroll
        for (int r = 0; r < 4; ++r) {
          float v = acc[i][j][r] + bv;
          if (OUT == 0)
            ((float*)Out)[(size_t)(row0 + r) * HID + col] = v;
          else if (OUT == 1)
            ((ushort*)Out)[(size_t)(row0 + r) * HID + col] = f2bf(v);
          else
            ((ushort*)Out)[(size_t)(row0 + r) * HID + col] = f2bf(v * QSCALE);
        }
      }
    }
}

__global__ __launch_bounds__(256) void gemm_qkv(const ushort* __restrict__ A0, const ushort* __restrict__ A1,
                                                const ushort* __restrict__ A2, const ushort* __restrict__ W0,
                                                const ushort* __restrict__ W1, const ushort* __restrict__ W2,
                                                const float* __restrict__ b0, const float* __restrict__ b1,
                                                const float* __restrict__ b2, ushort* __restrict__ O0,
                                                ushort* __restrict__ O1, ushort* __restrict__ O2) {
  __shared__ alignas(16) ushort As[128 * 32];
  __shared__ alignas(16) ushort Bs[128 * 32];
  // XCD-chunked: f%8 = XCD; each XCD owns 4 contiguous bm x all 8 bn
  const int f = blockIdx.y * 8 + blockIdx.x;  // 0..255
  const int xcd = f & 7, slot = f >> 3;       // slot 0..31
  const int bm = xcd * 4 + (slot >> 3);
  const int bn = slot & 7;
  const int z = blockIdx.z;
  if (z == 0)      gemm_body<128, 2>(A0, W0, b0, O0, As, Bs, bm, bn);  // Q pre-scaled
  else if (z == 1) gemm_body<128, 1>(A1, W1, b1, O1, As, Bs, bm, bn);  // K
  else             gemm_body<128, 3>(A2, W2, b2, O2, As, Bs, bm, bn);  // V -> VT
}

__global__ __launch_bounds__(256) void gemm_wo(const ushort* __restrict__ A, const ushort* __restrict__ W,
                                               const float* __restrict__ bias, float* __restrict__ O) {
  __shared__ alignas(16) ushort As[128 * 32];
  __shared__ alignas(16) ushort Bs[64 * 32];
  const int f = blockIdx.y * 16 + blockIdx.x;  // 0..511
  const int xcd = f & 7, slot = f >> 3;        // slot 0..63
  const int bm = xcd * 4 + (slot >> 4);
  const int bn = slot & 15;
  gemm_body<64, 0>(A, W, bias, O, As, Bs, bm, bn);
}

// ---------------- flash attention: EXACT round-5 kernel (passed, 63.4 us) ----------------
__device__ __forceinline__ short8 ldfrag(const char* tb, int r, int g) {
  return *reinterpret_cast<const short8*>(tb + r * 128 + ((g * 16) ^ ((r & 7) << 4)));
}

__global__ __launch_bounds__(512, 4) void attn_kernel(const ushort* __restrict__ Q,
                                                      const ushort* __restrict__ Kp,
                                                      const ushort* __restrict__ VT,
                                                      ushort* __restrict__ Op) {
  __shared__ alignas(16) ushort lds[32768];  // K: 4 tiles x 4096 ush; V: +16384. 64KB.

  const int bh = blockIdx.x;
  const int b = bh >> 4, h = bh & 15;
  const int qt = blockIdx.y;
  const int tid = threadIdx.x;
  const int w = tid >> 6, lane = tid & 63;
  const int q = lane & 31, hi = lane >> 5;
  const int qsub = w & 3, chf = w >> 2;

  const size_t base = (size_t)b * SEQ * HID + h * HD;
  const size_t vtbase = (size_t)bh * HD * SEQ;

  const int qrow = qt * 128 + qsub * 32 + q;
  short8 qf[4];
#pragma unroll
  for (int s = 0; s < 4; ++s)
    qf[s] = *reinterpret_cast<const short8*>(&Q[base + (size_t)qrow * HID + s * 16 + hi * 8]);

  f32x16 acc0 = (f32x16)(0.f), acc1 = (f32x16)(0.f);
  float mrun = -3e38f;
  float ps0 = 0.f, ps1 = 0.f, ps2 = 0.f, ps3 = 0.f;

  const int tsel = w >> 1, part = w & 1, sh = tsel & 1;
  const bool isK = tsel < 2;
  const int r8 = lane >> 3;
  const int sx = ((lane & 7) ^ r8) * 8;

  auto stage = [&](int buf, int ktb) {
    const int kt = ktb + sh * 16;
#pragma unroll
    for (int c = 0; c < 4; ++c) {
      const int G = part * 4 + c, r = G * 8 + r8;
      const ushort* src;
      ushort* dst;
      if (isK) {
        src = &Kp[base + (size_t)(kt * 64 + r) * HID + sx];
        dst = &lds[(sh * 2 + buf) * 4096 + G * 512];
      } else {
        src = &VT[vtbase + (size_t)r * SEQ + kt * 64 + sx];
        dst = &lds[16384 + (sh * 2 + buf) * 4096 + G * 512];
      }
      __builtin_amdgcn_global_load_lds((gptr_t)(const void*)src, (lptr_t)(void*)dst, 16, 0, 0);
    }
  };

  auto mkfrag = [&](const unsigned* Wg) -> short8 {
    unsigned X0 = (unsigned)__shfl_xor((int)Wg[0], 32, 64);
    unsigned X1 = (unsigned)__shfl_xor((int)Wg[1], 32, 64);
    unsigned X2 = (unsigned)__shfl_xor((int)Wg[2], 32, 64);
    unsigned X3 = (unsigned)__shfl_xor((int)Wg[3], 32, 64);
    union { unsigned u[4]; short8 v; } p;
    p.u[0] = hi ? X2 : Wg[0];
    p.u[1] = hi ? X3 : Wg[1];
    p.u[2] = hi ? Wg[2] : X0;
    p.u[3] = hi ? Wg[3] : X1;
    return p.v;
  };

  stage(0, 0);
  __syncthreads();

  int buf = 0;
  for (int ktb = 0; ktb < 16; ++ktb) {
    stage(buf ^ 1, (ktb + 1) & 15);

    const char* kb = (const char*)lds + (chf * 2 + buf) * 8192;
    const char* vb = (const char*)lds + 32768 + (chf * 2 + buf) * 8192;

    // ---- S^T = K Q^T ----
    f32x16 s0 = (f32x16)(0.f), s1 = (f32x16)(0.f);
#pragma unroll
    for (int cs = 0; cs < 4; ++cs) {
      short8 a = ldfrag(kb, q, cs * 2 + hi);
      s0 = __builtin_amdgcn_mfma_f32_32x32x16_bf16(a, qf[cs], s0, 0, 0, 0);
    }
#pragma unroll
    for (int cs = 0; cs < 4; ++cs) {
      short8 a = ldfrag(kb, 32 + q, cs * 2 + hi);
      s1 = __builtin_amdgcn_mfma_f32_32x32x16_bf16(a, qf[cs], s1, 0, 0, 0);
    }

    // ---- online softmax (exp2 domain), in-register ----
    float t8[8];
#pragma unroll
    for (int i = 0; i < 8; ++i)
      t8[i] = fmaxf(fmaxf(s0[i], s0[i + 8]), fmaxf(s1[i], s1[i + 8]));
    float pm = fmaxf(fmaxf(fmaxf(t8[0], t8[4]), fmaxf(t8[1], t8[5])),
                     fmaxf(fmaxf(t8[2], t8[6]), fmaxf(t8[3], t8[7])));
    pm = fmaxf(pm, __shfl_xor(pm, 32, 64));
    if (__any(pm > mrun + 8.f)) {  // defer-max (T13)
      const float mnew = fmaxf(mrun, pm);
      const float corr = __builtin_amdgcn_exp2f(mrun - mnew);
      mrun = mnew;
      ps0 *= corr; ps1 *= corr; ps2 *= corr; ps3 *= corr;
#pragma unroll
      for (int i = 0; i < 16; ++i) { acc0[i] *= corr; acc1[i] *= corr; }
    }
#pragma unroll
    for (int i = 0; i < 16; ++i) {
      s0[i] = __builtin_amdgcn_exp2f(s0[i] - mrun);
      s1[i] = __builtin_amdgcn_exp2f(s1[i] - mrun);
    }
    float a8[8];
#pragma unroll
    for (int i = 0; i < 8; ++i) a8[i] = (s0[i] + s0[i + 8]) + (s1[i] + s1[i + 8]);
    ps0 += a8[0] + a8[4]; ps1 += a8[1] + a8[5];
    ps2 += a8[2] + a8[6]; ps3 += a8[3] + a8[7];

    // ---- P pack + cross-half exchange + PV ----
    {
      unsigned W[8];
#pragma unroll
      for (int i = 0; i < 8; ++i) W[i] = cvt_pk_bf16(s0[2 * i], s0[2 * i + 1]);
      short8 p0 = mkfrag(W);
      short8 p1 = mkfrag(W + 4);
      short8 vf;
      vf = ldfrag(vb, q,      0 + hi); acc0 = __builtin_amdgcn_mfma_f32_32x32x16_bf16(vf, p0, acc0, 0, 0, 0);
      vf = ldfrag(vb, 32 + q, 0 + hi); acc1 = __builtin_amdgcn_mfma_f32_32x32x16_bf16(vf, p0, acc1, 0, 0, 0);
      vf = ldfrag(vb, q,      2 + hi); acc0 = __builtin_amdgcn_mfma_f32_32x32x16_bf16(vf, p1, acc0, 0, 0, 0);
      vf = ldfrag(vb, 32 + q, 2 + hi); acc1 = __builtin_amdgcn_mfma_f32_32x32x16_bf16(vf, p1, acc1, 0, 0, 0);
    }
    {
      unsigned W[8];
#pragma unroll
      for (int i = 0; i < 8; ++i) W[i] = cvt_pk_bf16(s1[2 * i], s1[2 * i + 1]);
      short8 p0 = mkfrag(W);
      short8 p1 = mkfrag(W + 4);
      short8 vf;
      vf = ldfrag(vb, q,      4 + hi); acc0 = __builtin_amdgcn_mfma_f32_32x32x16_bf16(vf, p0, acc0, 0, 0, 0);
      vf = ldfrag(vb, 32 + q, 4 + hi); acc1 = __builtin_amdgcn_mfma_f32_32x32x16_bf16(vf, p0, acc1, 0, 0, 0);
      vf = ldfrag(vb, q,      6 + hi); acc0 = __builtin_amdgcn_mfma_f32_32x32x16_bf16(vf, p1, acc0, 0, 0, 0);
      vf = ldfrag(vb, 32 + q, 6 + hi); acc1 = __builtin_amdgcn_mfma_f32_32x32x16_bf16(vf, p1, acc1, 0, 0, 0);
    }
    __syncthreads();
    buf ^= 1;
  }

  // ---- per-wave row sum ----
  float lsum = (ps0 + ps1) + (ps2 + ps3);
  const float lfull = lsum + __shfl_xor(lsum, 32, 64);

  // ---- combine kv-halves via LDS overlay ----
  __syncthreads();
  float* fl = (float*)lds;
  const int p = w & 3;
  float* ob = fl + p * 2048 + lane * 32;
  if (w >= 4) {
#pragma unroll
    for (int i = 0; i < 4; ++i) {
      f32x4 x = {acc0[4 * i], acc0[4 * i + 1], acc0[4 * i + 2], acc0[4 * i + 3]};
      *reinterpret_cast<f32x4*>(ob + 4 * (i ^ (lane & 7))) = x;
    }
#pragma unroll
    for (int i = 0; i < 4; ++i) {
      f32x4 x = {acc1[4 * i], acc1[4 * i + 1], acc1[4 * i + 2], acc1[4 * i + 3]};
      *reinterpret_cast<f32x4*>(ob + 4 * ((i + 4) ^ (lane & 7))) = x;
    }
    fl[8192 + (p * 64 + lane) * 2] = mrun;
    fl[8192 + (p * 64 + lane) * 2 + 1] = lfull;
  }
  __syncthreads();
  if (w < 4) {
    const float m1 = fl[8192 + (p * 64 + lane) * 2];
    const float l1 = fl[8192 + (p * 64 + lane) * 2 + 1];
    float o1[32];
#pragma unroll
    for (int s = 0; s < 8; ++s) {
      f32x4 x = *reinterpret_cast<const f32x4*>(ob + 4 * (s ^ (lane & 7)));
      o1[4 * s] = x[0]; o1[4 * s + 1] = x[1]; o1[4 * s + 2] = x[2]; o1[4 * s + 3] = x[3];
    }
    const float mnew = fmaxf(mrun, m1);
    const float c0 = __builtin_amdgcn_exp2f(mrun - mnew);
    const float c1 = __builtin_amdgcn_exp2f(m1 - mnew);
    const float linv = 1.f / (lfull * c0 + l1 * c1);
#pragma unroll
    for (int g = 0; g < 4; ++g) {
      {
        float x0 = (acc0[4 * g + 0] * c0 + o1[4 * g + 0] * c1) * linv;
        float x1 = (acc0[4 * g + 1] * c0 + o1[4 * g + 1] * c1) * linv;
        float x2 = (acc0[4 * g + 2] * c0 + o1[4 * g + 2] * c1) * linv;
        float x3 = (acc0[4 * g + 3] * c0 + o1[4 * g + 3] * c1) * linv;
        uint2 wd; wd.x = cvt_pk_bf16(x0, x1); wd.y = cvt_pk_bf16(x2, x3);
        *reinterpret_cast<uint2*>(&Op[base + (size_t)qrow * HID + g * 8 + hi * 4]) = wd;
      }
      {
        float x0 = (acc1[4 * g + 0] * c0 + o1[16 + 4 * g + 0] * c1) * linv;
        float x1 = (acc1[4 * g + 1] * c0 + o1[16 + 4 * g + 1] * c1) * linv;
        float x2 = (acc1[4 * g + 2] * c0 + o1[16 + 4 * g + 2] * c1) * linv;
        float x3 = (acc1[4 * g + 3] * c0 + o1[16 + 4 * g + 3] * c1) * linv;
        uint2 wd; wd.x = cvt_pk_bf16(x0, x1); wd.y = cvt_pk_bf16(x2, x3);
        *reinterpret_cast<uint2*>(&Op[base + (size_t)qrow * HID + 32 + g * 8 + hi * 4]) = wd;
      }
    }
  }
}

// ---------------- launch ----------------
extern "C" void kernel_launch(void* const* d_in, const int* in_sizes, int n_in,
                              void* d_out, int out_size, void* d_ws, size_t ws_size,
                              hipStream_t stream) {
  const float* query = (const float*)d_in[0];
  const float* key   = (const float*)d_in[1];
  const float* value = (const float*)d_in[2];
  const float* Wq = (const float*)d_in[3];
  const float* bq = (const float*)d_in[4];
  const float* Wk = (const float*)d_in[5];
  const float* bk = (const float*)d_in[6];
  const float* Wv = (const float*)d_in[7];
  const float* bv = (const float*)d_in[8];
  const float* Wo = (const float*)d_in[9];
  const float* bo = (const float*)d_in[10];

  const size_t actElems = (size_t)MS * HID;  // 4194304
  const size_t wElems = (size_t)HID * HID;   // 1048576
  char* ws = (char*)d_ws;
  ushort* qb = (ushort*)(ws + 0);
  ushort* kb = (ushort*)(ws + actElems * 2);
  ushort* vb = (ushort*)(ws + actElems * 4);
  ushort* wq = (ushort*)(ws + actElems * 6);
  ushort* wk = (ushort*)(ws + actElems * 6 + wElems * 2);
  ushort* wv = (ushort*)(ws + actElems * 6 + wElems * 4);
  ushort* wo = (ushort*)(ws + actElems * 6 + wElems * 6);
  ushort* Qp   = (ushort*)(ws + actElems * 6 + wElems * 8);
  ushort* Kp   = (ushort*)(ws + actElems * 8 + wElems * 8);
  ushort* VTp  = (ushort*)(ws + actElems * 10 + wElems * 8);
  ushort* XB   = (ushort*)(ws + actElems * 12 + wElems * 8);  // attn out

  cast_all<<<16384, 256, 0, stream>>>(query, key, value, Wq, Wk, Wv, Wo,
                                      qb, kb, vb, wq, wk, wv, wo);

  dim3 gq(8, 32, 3);  // 768 blocks, XCD-chunked inside
  gemm_qkv<<<gq, 256, 0, stream>>>(qb, kb, vb, wq, wk, wv, bq, bk, bv, Qp, Kp, VTp);

  dim3 ga(NB * NH, SEQ / 128);  // (32, 16) = 512 blocks x 512 threads; bh%8 pins XCD
  attn_kernel<<<ga, 512, 0, stream>>>(Qp, Kp, VTp, XB);

  dim3 go(16, 32);  // 512 blocks, XCD-chunked inside
  gemm_wo<<<go, 256, 0, stream>>>(XB, wo, bo, (float*)d_out);
}